// Round 3
// 820.046 us; speedup vs baseline: 1.2645x; 1.2645x over previous
//
#include <hip/hip_runtime.h>
#include <hip/hip_bf16.h>

#define HIDDEN 128
#define SCAN_TILE 1024     // elements per scan block (256 threads x 4)
#define SCAN_BLOCK 256     // threads per scan block

// ---------------------------------------------------------------------------
// CSR build step 1: zero row counters
// ---------------------------------------------------------------------------
__global__ void zero_counts(int* __restrict__ counts, int n) {
    int i = blockIdx.x * blockDim.x + threadIdx.x;
    int stride = gridDim.x * blockDim.x;
    for (; i < n; i += stride) counts[i] = 0;
}

// CSR build step 2: histogram of row degrees
__global__ void hist_kernel(const int* __restrict__ rows, int* __restrict__ counts, int E) {
    int i = blockIdx.x * blockDim.x + threadIdx.x;
    int stride = gridDim.x * blockDim.x;
    for (; i < E; i += stride) atomicAdd(&counts[rows[i]], 1);
}

// ---------------------------------------------------------------------------
// CSR build step 3: hierarchical exclusive scan (replaces the single-block
// scan that was 233 us / 23% of launch at 0.15% occupancy).
// Stage A: per-block partial sums (coalesced int4 loads, tree reduce)
// ---------------------------------------------------------------------------
__global__ void scan_partial_sums(const int* __restrict__ counts,
                                  int* __restrict__ block_sums,
                                  int n) {
    __shared__ int sdata[SCAN_BLOCK];
    int t = threadIdx.x;
    int idx = blockIdx.x * SCAN_TILE + t * 4;
    int s = 0;
    if (idx + 3 < n) {
        int4 c = *reinterpret_cast<const int4*>(counts + idx);
        s = c.x + c.y + c.z + c.w;
    } else if (idx < n) {
        s = counts[idx];
        if (idx + 1 < n) s += counts[idx + 1];
        if (idx + 2 < n) s += counts[idx + 2];
    }
    sdata[t] = s;
    __syncthreads();
    for (int off = SCAN_BLOCK / 2; off > 0; off >>= 1) {
        if (t < off) sdata[t] += sdata[t + off];
        __syncthreads();
    }
    if (t == 0) block_sums[blockIdx.x] = sdata[0];
}

// Stage B: single small block scans the block sums in place (exclusive),
// writes row_ptr[n] = total edge count.
__global__ void scan_block_offsets(int* __restrict__ block_sums,
                                   int* __restrict__ row_ptr,
                                   int nb, int n) {
    __shared__ int sdata[SCAN_BLOCK];
    int t = threadIdx.x;
    int chunk = (nb + SCAN_BLOCK - 1) / SCAN_BLOCK;
    int lo = t * chunk;
    int hi = min(lo + chunk, nb);
    int s = 0;
    for (int i = lo; i < hi; ++i) s += block_sums[i];
    sdata[t] = s;
    __syncthreads();
    // Hillis-Steele inclusive scan (read/write phases barrier-split)
    for (int off = 1; off < SCAN_BLOCK; off <<= 1) {
        int u = (t >= off) ? sdata[t - off] : 0;
        __syncthreads();
        sdata[t] += u;
        __syncthreads();
    }
    int run = sdata[t] - s;   // exclusive prefix of this thread's chunk
    for (int i = lo; i < hi; ++i) {
        int v = block_sums[i];
        block_sums[i] = run;
        run += v;
    }
    if (t == SCAN_BLOCK - 1) row_ptr[n] = sdata[SCAN_BLOCK - 1];
}

// Stage C: re-read counts, block-local exclusive scan + block offset,
// write row_ptr and cursor.
// NOTE: counts and cursor alias the same buffer (in-place). No __restrict__
// on them: each thread reads its 4 elements before overwriting them, and no
// other thread touches those addresses.
__global__ void scan_apply(const int* counts,
                           const int* __restrict__ block_offsets,
                           int* __restrict__ row_ptr,
                           int* cursor,
                           int n) {
    __shared__ int sdata[SCAN_BLOCK];
    int t = threadIdx.x;
    int idx = blockIdx.x * SCAN_TILE + t * 4;
    int v0 = 0, v1 = 0, v2 = 0, v3 = 0;
    if (idx + 3 < n) {
        int4 c = *reinterpret_cast<const int4*>(counts + idx);
        v0 = c.x; v1 = c.y; v2 = c.z; v3 = c.w;
    } else if (idx < n) {
        v0 = counts[idx];
        if (idx + 1 < n) v1 = counts[idx + 1];
        if (idx + 2 < n) v2 = counts[idx + 2];
    }
    int s = v0 + v1 + v2 + v3;
    sdata[t] = s;
    __syncthreads();
    for (int off = 1; off < SCAN_BLOCK; off <<= 1) {
        int u = (t >= off) ? sdata[t - off] : 0;
        __syncthreads();
        sdata[t] += u;
        __syncthreads();
    }
    int run = sdata[t] - s + block_offsets[blockIdx.x];
    if (idx < n)     { row_ptr[idx]     = run; cursor[idx]     = run; run += v0; }
    if (idx + 1 < n) { row_ptr[idx + 1] = run; cursor[idx + 1] = run; run += v1; }
    if (idx + 2 < n) { row_ptr[idx + 2] = run; cursor[idx + 2] = run; run += v2; }
    if (idx + 3 < n) { row_ptr[idx + 3] = run; cursor[idx + 3] = run; run += v3; }
}

// CSR build step 4: scatter edges into CSR slots
__global__ void scatter_kernel(const int* __restrict__ rows,
                               const int* __restrict__ cols,
                               const float* __restrict__ vals,
                               int* __restrict__ cursor,
                               int* __restrict__ csr_col,
                               float* __restrict__ csr_val,
                               int E) {
    int i = blockIdx.x * blockDim.x + threadIdx.x;
    int stride = gridDim.x * blockDim.x;
    for (; i < E; i += stride) {
        int r = rows[i];
        int pos = atomicAdd(&cursor[r], 1);
        csr_col[pos] = cols[i];
        csr_val[pos] = vals[i];
    }
}

// ---------------------------------------------------------------------------
// S0 = item_emb (float4 copy)
// ---------------------------------------------------------------------------
__global__ void copy_kernel(const float4* __restrict__ src, float4* __restrict__ dst, size_t n4) {
    size_t stride = (size_t)gridDim.x * blockDim.x;
    for (size_t i = (size_t)blockIdx.x * blockDim.x + threadIdx.x; i < n4; i += stride)
        dst[i] = src[i];
}

// ---------------------------------------------------------------------------
// CSR SpMM: one wave (64 lanes) per row; each lane owns float2 of hidden dim.
// Edge (col,val) loaded cooperatively, broadcast via __shfl. No atomics.
// FUSE_TOTAL: also writes t = s0 + s1 + s2 + acc (layer 3 only).
// ---------------------------------------------------------------------------
template <bool FUSE_TOTAL>
__global__ void spmm_csr(const int* __restrict__ row_ptr,
                         const int* __restrict__ csr_col,
                         const float* __restrict__ csr_val,
                         const float* __restrict__ x,
                         float* __restrict__ y,
                         const float* __restrict__ s0,
                         const float* __restrict__ s1,
                         const float* __restrict__ s2,
                         float* __restrict__ t_out,
                         int n_rows) {
    int wave = (int)(((size_t)blockIdx.x * blockDim.x + threadIdx.x) >> 6);
    int lane = threadIdx.x & 63;
    if (wave >= n_rows) return;

    int start = row_ptr[wave];
    int end   = row_ptr[wave + 1];

    const float2* X = (const float2*)x;
    float2 acc = make_float2(0.f, 0.f);

    for (int base = start; base < end; base += 64) {
        int idx = base + lane;
        int c = 0;
        float v = 0.f;
        if (idx < end) { c = csr_col[idx]; v = csr_val[idx]; }
        int n = min(64, end - base);
        for (int j = 0; j < n; ++j) {
            int   cj = __shfl(c, j);
            float vj = __shfl(v, j);
            float2 xv = X[(size_t)cj * 64 + lane];
            acc.x += vj * xv.x;
            acc.y += vj * xv.y;
        }
    }

    size_t out_idx = (size_t)wave * 64 + lane;
    ((float2*)y)[out_idx] = acc;

    if (FUSE_TOTAL) {
        float2 a = ((const float2*)s0)[out_idx];
        float2 b = ((const float2*)s1)[out_idx];
        float2 c2 = ((const float2*)s2)[out_idx];
        float2 o;
        o.x = a.x + b.x + c2.x + acc.x;
        o.y = a.y + b.y + c2.y + acc.y;
        ((float2*)t_out)[out_idx] = o;
    }
}

extern "C" void kernel_launch(void* const* d_in, const int* in_sizes, int n_in,
                              void* d_out, int out_size, void* d_ws, size_t ws_size,
                              hipStream_t stream) {
    const float* item_emb = (const float*)d_in[0];
    const int*   adj_rows = (const int*)d_in[1];
    const int*   adj_cols = (const int*)d_in[2];
    const float* adj_vals = (const float*)d_in[3];

    const size_t NH = (size_t)in_sizes[0];      // N * 128
    const int    E  = in_sizes[1];              // 1,600,000
    const int    N  = (int)(NH / HIDDEN);       // 100,000
    const size_t n4 = NH / 4;

    // d_out layout: [ total | S0 | S1 | S2 | S3 ], each NH floats
    float* T  = (float*)d_out;
    float* S0 = T + NH;
    float* S1 = S0 + NH;
    float* S2 = S1 + NH;
    float* S3 = S2 + NH;

    // Workspace layout (16B-aligned blocks) — byte-identical footprint to the
    // 1033us baseline kernel (no growth: ws_size may be exactly sized).
    char* ws = (char*)d_ws;
    int*   row_ptr    = (int*)ws;                    ws += ((size_t)(N + 1) * 4 + 15) & ~15ull;
    int*   cursor     = (int*)ws;                    ws += ((size_t)N * 4 + 15) & ~15ull;
    int*   csr_col    = (int*)ws;                    ws += ((size_t)E * 4 + 15) & ~15ull;
    float* csr_val    = (float*)ws;

    const int nb = (N + SCAN_TILE - 1) / SCAN_TILE;  // 98 scan blocks

    // block_sums scratch (nb ints, ~400 B): alias the TAIL of csr_col.
    // csr_col is only written by scatter_kernel, which is stream-ordered
    // AFTER scan_apply's last read of block_sums. Stays inside the baseline
    // workspace footprint; never touches d_out during the build phase.
    int* block_sums = csr_col + (E - nb);

    // ---- CSR build ----
    {
        int block = 256;
        int gridN = min((N + block - 1) / block, 4096);
        int gridE = min((E + block - 1) / block, 8192);
        zero_counts<<<gridN, block, 0, stream>>>(cursor, N);              // cursor as counts
        hist_kernel<<<gridE, block, 0, stream>>>(adj_rows, cursor, E);
        // hierarchical exclusive scan: counts(=cursor) -> row_ptr, cursor
        scan_partial_sums<<<nb, SCAN_BLOCK, 0, stream>>>(cursor, block_sums, N);
        scan_block_offsets<<<1, SCAN_BLOCK, 0, stream>>>(block_sums, row_ptr, nb, N);
        scan_apply<<<nb, SCAN_BLOCK, 0, stream>>>(cursor, block_sums, row_ptr, cursor, N);
        scatter_kernel<<<gridE, block, 0, stream>>>(adj_rows, adj_cols, adj_vals,
                                                    cursor, csr_col, csr_val, E);
    }

    // ---- S0 = item_emb ----
    {
        int block = 256;
        int grid = (int)min((n4 + block - 1) / block, (size_t)8192);
        copy_kernel<<<grid, block, 0, stream>>>((const float4*)item_emb, (float4*)S0, n4);
    }

    // ---- SpMM layers ----
    {
        int block = 256;                       // 4 waves per block
        int grid = (N * 64 + block - 1) / block;
        spmm_csr<false><<<grid, block, 0, stream>>>(row_ptr, csr_col, csr_val,
                                                    S0, S1, nullptr, nullptr, nullptr, nullptr, N);
        spmm_csr<false><<<grid, block, 0, stream>>>(row_ptr, csr_col, csr_val,
                                                    S1, S2, nullptr, nullptr, nullptr, nullptr, N);
        spmm_csr<true><<<grid, block, 0, stream>>>(row_ptr, csr_col, csr_val,
                                                   S2, S3, S0, S1, S2, T, N);
    }
}